// Round 15
// baseline (849.343 us; speedup 1.0000x reference)
//
#include <hip/hip_runtime.h>
#include <stdint.h>

#define ATOM_FDIM 133
#define BOND_FDIM 147
#define HIDDEN    300
#define N_ATOMS   100000
#define N_BONDS   200000
#define MAX_NB    6
#define N_MOLS    4000

#define KP_I 192      // padded K for W_i GEMM (147), 64-multiple
#define KP_H 320      // padded K for W_h GEMM (300)
#define KP_O 512      // padded K for output GEMM (433, reordered amsg|f_atoms|0), 64-mult
#define LDA  304      // activation row stride in elems (608B, 16B-aligned)
#define CPR  38       // uint4 chunks per activation row (304/8)

#define TM   128      // GEMM tile rows
#define BCH  20       // B chunks (1KB) per K32-half (NPAD = 320)

typedef unsigned short u16;
typedef short bf16x8 __attribute__((ext_vector_type(8)));
typedef float f32x4 __attribute__((ext_vector_type(4)));

__device__ __forceinline__ u16 f2bu(float f) {            // f32 -> bf16 (RNE)
    unsigned u = __float_as_uint(f);
    u += 0x7FFFu + ((u >> 16) & 1u);
    return (u16)(u >> 16);
}
__device__ __forceinline__ float bu2f(u16 b) { return __uint_as_float(((unsigned)b) << 16); }

__device__ __forceinline__ uint4 relu_bf16x8(uint4 v) {
    union { uint4 u; u16 s[8]; } x, o;
    x.u = v;
    #pragma unroll
    for (int e = 0; e < 8; ++e) o.s[e] = (x.s[e] & 0x8000u) ? (u16)0 : x.s[e];
    return o.u;
}
__device__ __forceinline__ uint4 comb_bf16x8(uint4 vi, uint4 va, uint4 vy) {
    union { uint4 u; u16 s[8]; } xi, xa, xy, o;
    xi.u = vi; xa.u = va; xy.u = vy;
    #pragma unroll
    for (int e = 0; e < 8; ++e)
        o.s[e] = f2bu(fmaxf(bu2f(xi.s[e]) + bu2f(xa.s[e]) - bu2f(xy.s[e]), 0.f));
    return o.u;
}

#define AS1 __attribute__((address_space(1)))
#define AS3 __attribute__((address_space(3)))
__device__ __forceinline__ void gl_lds(const void* g, void* l) {
    __builtin_amdgcn_global_load_lds((const AS1 void*)g, (AS3 void*)l, 16, 0, 0);
}
#define MFMA(a, b, c) __builtin_amdgcn_mfma_f32_16x16x32_bf16((a), (b), (c), 0, 0, 0)

// ---------- dense-A bf16 MFMA GEMM, BK=64 (2 K-halves per step) ----------
// Block 128x320, 512 thr (8 waves 4x2), wave 32x160 = 2x10 frags.
// LDS: A tri 3x16KB + B dbl 2x40KB = 128KB. Per step: 4 barriers, 1 gate,
// 24 ds_read, 40 MFMA. B staged into Bs[(tt+1)&1] -- UNWRAPPED step parity
// (r14 bug: wrapped w1&1 clobbered the live buffer at the last step for odd NT).
// Gate vmcnt(2) keeps only A(t+2); retires A(t+1)+B(t+1). Never drains.
// EPI 1: raw | 2: relu(v+bias)
template <int EPI>
__global__ __launch_bounds__(512, 2) void mm_k(
    const u16* __restrict__ A, int lda,
    const u16* __restrict__ Wp,
    const float* __restrict__ bias,
    u16* __restrict__ out0, int ldo0,
    int M, int NT)                       // NT = Kp/64 >= 3
{
    __shared__ __align__(16) u16 As[3][16 * 512];   // [buf][(half*8+wid)*512]
    __shared__ __align__(16) u16 Bs[2][40 * 512];   // [buf][(half*20+c)*512]

    const int t    = threadIdx.x;
    const int lane = t & 63, wid = t >> 6;
    const int fl   = lane & 15, fh = lane >> 4;
    const int m0   = blockIdx.x * TM;
    const int wr   = wid >> 1, wc = wid & 1;

    int arow = m0 + wid * 16 + fl;
    if (arow > M - 1) arow = M - 1;
    const char* srcAp = (const char*)A + (size_t)arow * (size_t)lda * 2u + (size_t)(fh * 16);
    const char* WpC = (const char*)Wp;
    const size_t srcB0 = (size_t)(5 * wid) * 1024u + (size_t)lane * 16u;

    f32x4 acc[2][10] = {};

#define STAGE_A(kt, buf) do {                                                      \
        gl_lds(srcAp + (size_t)(kt) * 128u,      (char*)As[buf] + wid * 1024);     \
        gl_lds(srcAp + (size_t)(kt) * 128u + 64, (char*)As[buf] + 8192 + wid * 1024); \
    } while (0)
#define STAGE_B(kt, buf) do {                                                      \
        const size_t kb_ = (size_t)(kt) * 40960u;                                  \
        _Pragma("unroll")                                                          \
        for (int j = 0; j < 5; ++j)                                                \
            gl_lds(WpC + kb_ + srcB0 + (size_t)j * 1024,                           \
                   (char*)Bs[buf] + 5 * wid * 1024 + j * 1024);                    \
    } while (0)

    STAGE_A(0, 0);
    STAGE_B(0, 0);
    STAGE_A(1, 1);
    asm volatile("s_waitcnt vmcnt(2)" ::: "memory");
    __builtin_amdgcn_s_barrier();

    int cur = 0;
    for (int tt = 0; tt < NT; ++tt) {
        int w1 = tt + 1; if (w1 >= NT) w1 -= NT;
        int w2 = tt + 2; if (w2 >= NT) w2 -= NT;
        const int nx1 = (cur < 2) ? cur + 1 : 0;
        const int nx2 = (nx1 < 2) ? nx1 + 1 : 0;
        const u16* as_c = As[cur];
        const u16* bs_c = Bs[tt & 1];

        bf16x8 af0, af1, bfv[10];
        // ---------- phase 1: K-half 0 ----------
        af0 = *reinterpret_cast<const bf16x8*>(&as_c[(wr * 2 + 0) * 512 + lane * 8]);
        af1 = *reinterpret_cast<const bf16x8*>(&as_c[(wr * 2 + 1) * 512 + lane * 8]);
        #pragma unroll
        for (int n = 0; n < 10; ++n)
            bfv[n] = *reinterpret_cast<const bf16x8*>(&bs_c[(wc * 10 + n) * 512 + lane * 8]);
        STAGE_B(w1, (tt + 1) & 1);   // UNWRAPPED parity: never the live buffer
        __builtin_amdgcn_s_barrier();
        __builtin_amdgcn_s_setprio(1);
        #pragma unroll
        for (int n = 0; n < 10; ++n) {
            acc[0][n] = MFMA(af0, bfv[n], acc[0][n]);
            acc[1][n] = MFMA(af1, bfv[n], acc[1][n]);
        }
        __builtin_amdgcn_s_setprio(0);
        __builtin_amdgcn_s_barrier();

        // ---------- phase 2: K-half 1 ----------
        af0 = *reinterpret_cast<const bf16x8*>(&as_c[(8 + wr * 2 + 0) * 512 + lane * 8]);
        af1 = *reinterpret_cast<const bf16x8*>(&as_c[(8 + wr * 2 + 1) * 512 + lane * 8]);
        #pragma unroll
        for (int n = 0; n < 10; ++n)
            bfv[n] = *reinterpret_cast<const bf16x8*>(&bs_c[(20 + wc * 10 + n) * 512 + lane * 8]);
        STAGE_A(w2, nx2);
        asm volatile("s_waitcnt vmcnt(2)" ::: "memory");   // retire A(t+1)+B(t+1); keep A(t+2)
        __builtin_amdgcn_s_barrier();
        __builtin_amdgcn_s_setprio(1);
        #pragma unroll
        for (int n = 0; n < 10; ++n) {
            acc[0][n] = MFMA(af0, bfv[n], acc[0][n]);
            acc[1][n] = MFMA(af1, bfv[n], acc[1][n]);
        }
        __builtin_amdgcn_s_setprio(0);
        __builtin_amdgcn_s_barrier();
        cur = nx1;
    }
#undef STAGE_A
#undef STAGE_B

    #pragma unroll
    for (int m = 0; m < 2; ++m) {
        #pragma unroll
        for (int r = 0; r < 4; ++r) {
            const int row = m0 + wr * 32 + m * 16 + fh * 4 + r;
            if (row >= M) continue;
            #pragma unroll
            for (int n = 0; n < 10; ++n) {
                const int col = wc * 160 + n * 16 + fl;
                if (col >= HIDDEN) continue;
                const float v = acc[m][n][r];
                if (EPI == 1) out0[(size_t)row * ldo0 + col] = f2bu(v);
                else          out0[(size_t)row * ldo0 + col] = f2bu(fmaxf(v + bias[col], 0.f));
            }
        }
    }
}

// ---------- fused-A bf16 MFMA GEMM, BK=64, reg-staged A ----------
// AM1: A' = relu(inp) | AM2: A' = relu(inp + aY[b2a] - Y[b2revb]). Raw out.
// LDS: A dbl 2x16KB + B dbl 2x40KB = 112KB. B staged into Bs[(tt+1)&1]
// (unwrapped parity -- r14 wrap-clobber fix). Gate vmcnt(2)/(6) keeps L-regs.
template <int AM>
__global__ __launch_bounds__(512, 2) void mmf_k(
    const u16* __restrict__ A, int lda,          // inp
    const u16* __restrict__ aYp,                 // AM2
    const u16* __restrict__ Yp,                  // AM2
    const int* __restrict__ b2a,                 // AM2
    const int* __restrict__ b2revb,              // AM2
    const u16* __restrict__ Wp,
    u16* __restrict__ out0, int ldo0,
    int M, int NT)                               // NT = Kp/64 >= 2
{
    __shared__ __align__(16) u16 As[2][16 * 512];   // 2 x 16 KB
    __shared__ __align__(16) u16 Bs[2][40 * 512];   // 2 x 40 KB

    const int t    = threadIdx.x;
    const int lane = t & 63, wid = t >> 6;
    const int fl   = lane & 15, fh = lane >> 4;
    const int m0   = blockIdx.x * TM;
    const int wr   = wid >> 1, wc = wid & 1;

    int arow = m0 + wid * 16 + fl;
    if (arow > M - 1) arow = M - 1;
    const char* pI = (const char*)A + (size_t)arow * (size_t)lda * 2u + (size_t)(fh * 16);
    const char* pA = nullptr; const char* pY = nullptr;
    if constexpr (AM == 2) {
        const int ia = b2a[arow], ir = b2revb[arow];
        pA = (const char*)aYp + (size_t)ia * (LDA * 2) + (size_t)(fh * 16);
        pY = (const char*)Yp  + (size_t)ir * (LDA * 2) + (size_t)(fh * 16);
    }
    const char* WpC = (const char*)Wp;
    const size_t srcB0 = (size_t)(5 * wid) * 1024u + (size_t)lane * 16u;

    f32x4 acc[2][10] = {};
    uint4 Xi0, Xi1, Xa0, Xa1, Xy0, Xy1;
    uint4 Yi0, Yi1, Ya0, Ya1, Yy0, Yy1;
    (void)Xa0; (void)Xa1; (void)Xy0; (void)Xy1;
    (void)Ya0; (void)Ya1; (void)Yy0; (void)Yy1;

#define STAGE_B(kt, buf) do {                                                      \
        const size_t kb_ = (size_t)(kt) * 40960u;                                  \
        _Pragma("unroll")                                                          \
        for (int j = 0; j < 5; ++j)                                                \
            gl_lds(WpC + kb_ + srcB0 + (size_t)j * 1024,                           \
                   (char*)Bs[buf] + 5 * wid * 1024 + j * 1024);                    \
    } while (0)
#define LOADSET(kt, I0, I1, A0, A1, Y0, Y1) do {                                   \
        const size_t kb_ = (size_t)(kt) * 128u;                                    \
        I0 = *reinterpret_cast<const uint4*>(pI + kb_);                            \
        I1 = *reinterpret_cast<const uint4*>(pI + kb_ + 64);                       \
        if constexpr (AM == 2) {                                                   \
            A0 = *reinterpret_cast<const uint4*>(pA + kb_);                        \
            A1 = *reinterpret_cast<const uint4*>(pA + kb_ + 64);                   \
            Y0 = *reinterpret_cast<const uint4*>(pY + kb_);                        \
            Y1 = *reinterpret_cast<const uint4*>(pY + kb_ + 64);                   \
        }                                                                          \
    } while (0)
#define XF(I, Aa, Yy) (AM == 2 ? comb_bf16x8(I, Aa, Yy) : relu_bf16x8(I))

    // ---- prologue: X(tile0) regs, B(0), Y(tile1) regs; write A(0); wait B(0) ----
    LOADSET(0, Xi0, Xi1, Xa0, Xa1, Xy0, Xy1);
    STAGE_B(0, 0);
    LOADSET(1, Yi0, Yi1, Ya0, Ya1, Yy0, Yy1);
    if constexpr (AM == 2) asm volatile("s_waitcnt vmcnt(11)" ::: "memory");
    else                   asm volatile("s_waitcnt vmcnt(7)"  ::: "memory");
    *reinterpret_cast<uint4*>(&As[0][wid * 512 + lane * 8])       = XF(Xi0, Xa0, Xy0);
    *reinterpret_cast<uint4*>(&As[0][(8 + wid) * 512 + lane * 8]) = XF(Xi1, Xa1, Xy1);
    if constexpr (AM == 2) asm volatile("s_waitcnt vmcnt(6)" ::: "memory");
    else                   asm volatile("s_waitcnt vmcnt(2)" ::: "memory");
    asm volatile("s_waitcnt lgkmcnt(0)" ::: "memory");
    __builtin_amdgcn_s_barrier();

    int tt = 0;

#define STEP(LI0, LI1, LA0, LA1, LY0, LY1, WI0, WI1, WA0, WA1, WY0, WY1) do {               \
    int w1 = tt + 1; if (w1 >= NT) w1 -= NT;                                                \
    int w2 = tt + 2; if (w2 >= NT) w2 -= NT;                                                \
    const u16* as_c = As[tt & 1];                                                           \
    const u16* bs_c = Bs[tt & 1];                                                           \
    bf16x8 af0, af1, bfv[10];                                                               \
    /* phase 1: K-half 0 */                                                                 \
    af0 = *reinterpret_cast<const bf16x8*>(&as_c[(wr * 2 + 0) * 512 + lane * 8]);           \
    af1 = *reinterpret_cast<const bf16x8*>(&as_c[(wr * 2 + 1) * 512 + lane * 8]);           \
    _Pragma("unroll")                                                                       \
    for (int n = 0; n < 10; ++n)                                                            \
        bfv[n] = *reinterpret_cast<const bf16x8*>(&bs_c[(wc * 10 + n) * 512 + lane * 8]);   \
    STAGE_B(w1, (tt + 1) & 1);  /* UNWRAPPED parity */                                      \
    LOADSET(w2, LI0, LI1, LA0, LA1, LY0, LY1);                                              \
    __builtin_amdgcn_s_barrier();                                                           \
    __builtin_amdgcn_s_setprio(1);                                                          \
    _Pragma("unroll")                                                                       \
    for (int n = 0; n < 10; ++n) {                                                          \
        acc[0][n] = MFMA(af0, bfv[n], acc[0][n]);                                           \
        acc[1][n] = MFMA(af1, bfv[n], acc[1][n]);                                           \
    }                                                                                       \
    __builtin_amdgcn_s_setprio(0);                                                          \
    __builtin_amdgcn_s_barrier();                                                           \
    /* phase 2: K-half 1 */                                                                 \
    af0 = *reinterpret_cast<const bf16x8*>(&as_c[(8 + wr * 2 + 0) * 512 + lane * 8]);       \
    af1 = *reinterpret_cast<const bf16x8*>(&as_c[(8 + wr * 2 + 1) * 512 + lane * 8]);       \
    _Pragma("unroll")                                                                       \
    for (int n = 0; n < 10; ++n)                                                            \
        bfv[n] = *reinterpret_cast<const bf16x8*>(&bs_c[(20 + wc * 10 + n) * 512 + lane * 8]); \
    if constexpr (AM == 2) asm volatile("s_waitcnt vmcnt(6)" ::: "memory");                 \
    else                   asm volatile("s_waitcnt vmcnt(2)" ::: "memory");                 \
    *reinterpret_cast<uint4*>(&As[(tt + 1) & 1][wid * 512 + lane * 8])       = XF(WI0, WA0, WY0); \
    *reinterpret_cast<uint4*>(&As[(tt + 1) & 1][(8 + wid) * 512 + lane * 8]) = XF(WI1, WA1, WY1); \
    asm volatile("s_waitcnt lgkmcnt(0)" ::: "memory");                                      \
    __builtin_amdgcn_s_barrier();                                                           \
    __builtin_amdgcn_s_setprio(1);                                                          \
    _Pragma("unroll")                                                                       \
    for (int n = 0; n < 10; ++n) {                                                          \
        acc[0][n] = MFMA(af0, bfv[n], acc[0][n]);                                           \
        acc[1][n] = MFMA(af1, bfv[n], acc[1][n]);                                           \
    }                                                                                       \
    __builtin_amdgcn_s_setprio(0);                                                          \
    __builtin_amdgcn_s_barrier();                                                           \
    ++tt;                                                                                   \
} while (0)

    while (tt + 1 < NT) {
        STEP(Xi0, Xi1, Xa0, Xa1, Xy0, Xy1, Yi0, Yi1, Ya0, Ya1, Yy0, Yy1);
        STEP(Yi0, Yi1, Ya0, Ya1, Yy0, Yy1, Xi0, Xi1, Xa0, Xa1, Xy0, Xy1);
    }
    if (tt < NT) STEP(Xi0, Xi1, Xa0, Xa1, Xy0, Xy1, Yi0, Yi1, Ya0, Ya1, Yy0, Yy1);
#undef STEP
#undef LOADSET
#undef STAGE_B
#undef XF

    #pragma unroll
    for (int m = 0; m < 2; ++m) {
        #pragma unroll
        for (int r = 0; r < 4; ++r) {
            const int row = m0 + wr * 32 + m * 16 + fh * 4 + r;
            if (row >= M) continue;
            #pragma unroll
            for (int n = 0; n < 10; ++n) {
                const int col = wc * 160 + n * 16 + fl;
                if (col >= HIDDEN) continue;
                out0[(size_t)row * ldo0 + col] = f2bu(acc[m][n][r]);
            }
        }
    }
}

// ---- weight -> staged panel layout [NT32][20][512] with optional K-row remap ----
__global__ __launch_bounds__(256) void wconv_k(const float* __restrict__ W,
                                               int split, int off1, int Ktot, int NT32,
                                               u16* __restrict__ Wp)
{
    const int id = blockIdx.x * 256 + threadIdx.x;
    if (id >= NT32 * BCH * 512) return;
    const int block = id >> 9, rem = id & 511;
    const int l = rem >> 3, e = rem & 7;
    const int c = block % BCH, kt = block / BCH;
    const int col = c * 16 + (l & 15);
    const int k   = kt * 32 + (l >> 4) * 8 + e;
    float v = 0.f;
    if (col < HIDDEN) {
        if (k < split) {
            const int r = k + off1;
            if (r < Ktot) v = W[(size_t)r * HIDDEN + col];
        } else {
            const int r = k - split;
            if (r < off1) v = W[(size_t)r * HIDDEN + col];
        }
    }
    Wp[id] = f2bu(v);
}

// ---- f_bonds f32 -> bf16 padded [200000][192] ----
__global__ __launch_bounds__(256) void fbconv_k(const float* __restrict__ fb, u16* __restrict__ dst)
{
    const int id = blockIdx.x * 256 + threadIdx.x;
    if (id >= N_BONDS * KP_I) return;
    const int r = id / KP_I, k = id - r * KP_I;
    dst[id] = f2bu(k < BOND_FDIM ? fb[(size_t)r * BOND_FDIM + k] : 0.f);
}

// ---- dst[a][:] = sum_j src[a2b[a][j]][:]   (16B chunks, stride LDA) ----
__global__ __launch_bounds__(256) void agg_k(const u16* __restrict__ src,
                                             const int* __restrict__ a2b,
                                             u16* __restrict__ dst)
{
    const int c = blockIdx.x * 256 + threadIdx.x;
    if (c >= N_ATOMS * CPR) return;
    const int a = c / CPR, q = c - a * CPR;
    const int h = q * 8;
    const int* nb = a2b + (size_t)a * MAX_NB;
    float s[8] = {};
    #pragma unroll
    for (int j = 0; j < MAX_NB; ++j) {
        const int r = nb[j];
        union { uint4 u; u16 s[8]; } x;
        x.u = *(const uint4*)(src + (size_t)r * LDA + h);
        #pragma unroll
        for (int e = 0; e < 8; ++e) s[e] += bu2f(x.s[e]);
    }
    union { uint4 u; u16 s[8]; } o;
    #pragma unroll
    for (int e = 0; e < 8; ++e) o.s[e] = f2bu(s[e]);
    *(uint4*)(dst + (size_t)a * LDA + h) = o.u;
}

// ---- msg[b] = relu(inp[b] + aY[b2a[b]] - Y[b2revb[b]])   (16B chunks) ----
__global__ __launch_bounds__(256) void comb_k(const u16* __restrict__ inp,
                                              const u16* __restrict__ aY,
                                              const u16* __restrict__ Y,
                                              const int* __restrict__ b2a,
                                              const int* __restrict__ b2revb,
                                              u16* __restrict__ msg)
{
    const int c = blockIdx.x * 256 + threadIdx.x;
    if (c >= N_BONDS * CPR) return;
    const int b = c / CPR, q = c - b * CPR;
    const int h = q * 8;
    const int ia = b2a[b], ir = b2revb[b];
    union { uint4 u; u16 s[8]; } xi, xa, xy, o;
    xi.u = *(const uint4*)(inp + (size_t)b * LDA + h);
    xa.u = *(const uint4*)(aY + (size_t)ia * LDA + h);
    xy.u = *(const uint4*)(Y + (size_t)ir * LDA + h);
    #pragma unroll
    for (int j = 0; j < 8; ++j)
        o.s[j] = f2bu(fmaxf(bu2f(xi.s[j]) + bu2f(xa.s[j]) - bu2f(xy.s[j]), 0.f));
    *(uint4*)(msg + (size_t)b * LDA + h) = o.u;
}

// ---- fused final agg + concat (REORDERED, stride 512): dst[a][k] =
//      k<300: sum_j msg[a2b[a][j]][k] | k<433: f_atoms[a][k-300] | 0 ----
__global__ __launch_bounds__(256) void aggcat_k(const u16* __restrict__ msg,
                                                const int* __restrict__ a2b,
                                                const float* __restrict__ fa,
                                                u16* __restrict__ dst)
{
    const int id = blockIdx.x * 256 + threadIdx.x;
    if (id >= N_ATOMS * (KP_O / 4)) return;
    const int a = id / (KP_O / 4), c = id - a * (KP_O / 4);
    const int e0 = c * 4;
    union { uint2 u; u16 s[4]; } o;
    if (e0 < HIDDEN) {
        const int* nb = a2b + (size_t)a * MAX_NB;
        float s0 = 0.f, s1 = 0.f, s2 = 0.f, s3 = 0.f;
        #pragma unroll
        for (int j = 0; j < MAX_NB; ++j) {
            union { uint2 u; u16 s[4]; } x;
            x.u = *(const uint2*)(msg + (size_t)nb[j] * LDA + e0);
            s0 += bu2f(x.s[0]); s1 += bu2f(x.s[1]); s2 += bu2f(x.s[2]); s3 += bu2f(x.s[3]);
        }
        o.s[0] = f2bu(s0); o.s[1] = f2bu(s1); o.s[2] = f2bu(s2); o.s[3] = f2bu(s3);
    } else {
        #pragma unroll
        for (int j = 0; j < 4; ++j) {
            const int fi = e0 + j - HIDDEN;
            o.s[j] = (fi >= 0 && fi < ATOM_FDIM) ? f2bu(fa[(size_t)a * ATOM_FDIM + fi]) : (u16)0;
        }
    }
    *(uint2*)(dst + (size_t)a * KP_O + e0) = o.u;
}

// ---- per-mol mean over sorted atom2mol ----
__global__ __launch_bounds__(320) void pool_k(const u16* __restrict__ ah,
                                              const int* __restrict__ a2m,
                                              float* __restrict__ out)
{
    const int m = blockIdx.x;
    int lo, hi;
    { int l = 0, r = N_ATOMS;
      while (l < r) { int mid = (l + r) >> 1; if (a2m[mid] < m) l = mid + 1; else r = mid; }
      lo = l; }
    { int l = lo, r = N_ATOMS;
      while (l < r) { int mid = (l + r) >> 1; if (a2m[mid] < m + 1) l = mid + 1; else r = mid; }
      hi = l; }
    const float inv = 1.0f / (float)((hi - lo) > 1 ? (hi - lo) : 1);
    const int h = threadIdx.x;
    if (h >= HIDDEN) return;
    float s = 0.f;
    for (int a = lo; a < hi; ++a) s += bu2f(ah[(size_t)a * LDA + h]);
    out[(size_t)m * HIDDEN + h] = s * inv;
}

extern "C" void kernel_launch(void* const* d_in, const int* in_sizes, int n_in,
                              void* d_out, int out_size, void* d_ws, size_t ws_size,
                              hipStream_t stream)
{
    const float* f_atoms  = (const float*)d_in[0];
    const float* f_bonds  = (const float*)d_in[1];
    const int*   a2b      = (const int*)d_in[2];
    const int*   b2a      = (const int*)d_in[3];
    const int*   b2revb   = (const int*)d_in[4];
    const int*   atom2mol = (const int*)d_in[5];
    const float* W_i      = (const float*)d_in[6];
    const float* W_h      = (const float*)d_in[7];
    const float* W_o_w    = (const float*)d_in[8];
    const float* W_o_b    = (const float*)d_in[9];
    float* out = (float*)d_out;

    // ---- workspace (bf16 as u16); +16 rows slack per big buffer ----
    char* p = (char*)d_ws;
    auto alloc = [&](size_t bytes) { char* r = p; p += (bytes + 255) & ~(size_t)255; return r; };
    u16* B0 = (u16*)alloc(((size_t)N_BONDS + 16) * LDA * 2);   // inp -> ah
    u16* B1 = (u16*)alloc(((size_t)N_BONDS + 16) * LDA * 2);   // fb16 -> Y1 -> msg2
    u16* B2 = (u16*)alloc(((size_t)N_BONDS + 16) * LDA * 2);   // Y2 -> concat (100k x 512)
    u16* aY = (u16*)alloc(((size_t)N_ATOMS + 16) * LDA * 2);
    u16* Wpi = (u16*)alloc((size_t)(KP_I / 32) * BCH * 512 * 2);
    u16* Wph = (u16*)alloc((size_t)(KP_H / 32) * BCH * 512 * 2);
    u16* Wpo = (u16*)alloc((size_t)(KP_O / 32) * BCH * 512 * 2);
    if ((size_t)(p - (char*)d_ws) > ws_size) return;

    u16* inp    = B0;
    u16* fb16   = B1;   // [200000][192], dead after mm0
    u16* Y1     = B1;   // after fb16 dead
    u16* Y2     = B2;
    u16* msg2   = B1;   // Y1 dead after AM2 GEMM
    u16* concat = B2;   // [100000][512]; Y2 dead after comb
    u16* ah     = B0;   // inp dead after comb

    const dim3 blk(256);
    auto g1 = [](long long n) { return dim3((unsigned)((n + 255) / 256)); };
    const dim3 blk5(512);
    const dim3 gB((N_BONDS + TM - 1) / TM);   // 1563
    const dim3 gA((N_ATOMS + TM - 1) / TM);   //  782

    const int BIGSPLIT = 1 << 20;
    wconv_k<<<g1((long long)(KP_I / 32) * BCH * 512), blk, 0, stream>>>(
        W_i, BIGSPLIT, 0, BOND_FDIM, KP_I / 32, Wpi);
    wconv_k<<<g1((long long)(KP_H / 32) * BCH * 512), blk, 0, stream>>>(
        W_h, BIGSPLIT, 0, HIDDEN, KP_H / 32, Wph);
    wconv_k<<<g1((long long)(KP_O / 32) * BCH * 512), blk, 0, stream>>>(
        W_o_w, HIDDEN, ATOM_FDIM, ATOM_FDIM + HIDDEN, KP_O / 32, Wpo);
    fbconv_k<<<g1((long long)N_BONDS * KP_I), blk, 0, stream>>>(f_bonds, fb16);

    // inp = f_bonds @ W_i (raw; relu fused into AM1's A-stage)  [dense path]
    mm_k<1><<<gB, blk5, 0, stream>>>(fb16, KP_I, Wpi, nullptr,
                                     inp, LDA, N_BONDS, KP_I / 64);

    // iter 1: Y1 = relu(inp) @ W_h   [fused]
    mmf_k<1><<<gB, blk5, 0, stream>>>(inp, LDA, nullptr, nullptr, nullptr, nullptr,
                                      Wph, Y1, LDA, N_BONDS, KP_H / 64);
    agg_k<<<g1((long long)N_ATOMS * CPR), blk, 0, stream>>>(Y1, a2b, aY);

    // iter 2: Y2 = relu(inp + aY[b2a] - Y1[b2revb]) @ W_h   [fused]
    mmf_k<2><<<gB, blk5, 0, stream>>>(inp, LDA, aY, Y1, b2a, b2revb,
                                      Wph, Y2, LDA, N_BONDS, KP_H / 64);
    agg_k<<<g1((long long)N_ATOMS * CPR), blk, 0, stream>>>(Y2, a2b, aY);

    // msg2 materialized (feeds the 6-way aggcat gather)
    comb_k<<<g1((long long)N_BONDS * CPR), blk, 0, stream>>>(inp, aY, Y2, b2a, b2revb, msg2);
    aggcat_k<<<g1((long long)N_ATOMS * (KP_O / 4)), blk, 0, stream>>>(msg2, a2b, f_atoms, concat);

    // output GEMM  [dense path]
    mm_k<2><<<gA, blk5, 0, stream>>>(concat, KP_O, Wpo, W_o_b,
                                     ah, LDA, N_ATOMS, KP_O / 64);
    pool_k<<<dim3(N_MOLS), dim3(320), 0, stream>>>(ah, atom2mol, out);
}